// Round 6
// baseline (455.565 us; speedup 1.0000x reference)
//
#include <hip/hip_runtime.h>

typedef short bf16x8 __attribute__((ext_vector_type(8)));
typedef float f32x4 __attribute__((ext_vector_type(4)));

__device__ __forceinline__ ushort f2bf(float f) {
    union { float f; unsigned u; } v; v.f = f;
    unsigned r = (v.u + 0x7fffu + ((v.u >> 16) & 1u)) >> 16;
    return (ushort)r;
}
__device__ __forceinline__ float bf2f(ushort u) {
    union { unsigned u; float f; } v; v.u = ((unsigned)u) << 16;
    return v.f;
}
__device__ __forceinline__ void async_copy16(void* lds, const void* g) {
    __builtin_amdgcn_global_load_lds(
        (const __attribute__((address_space(1))) unsigned*)g,
        (__attribute__((address_space(3))) unsigned*)lds, 16, 0, 0);
}

// ---------------- fp32 -> bf16 conversion ----------------
__global__ __launch_bounds__(256)
void cvt_f32_bf16(const float* __restrict__ src, ushort* __restrict__ dst, int n) {
    int i = (blockIdx.x * 256 + threadIdx.x) * 4;
    if (i >= n) return;
    float4 v = *(const float4*)(src + i);
    ushort4 o;
    o.x = f2bf(v.x); o.y = f2bf(v.y); o.z = f2bf(v.z); o.w = f2bf(v.w);
    *(ushort4*)(dst + i) = o;
}

// fused weight conversion: Wq|Wk|Wv (3 x 262144) -> contiguous bf16 stack
__global__ __launch_bounds__(256)
void cvt_w(const float* __restrict__ a, const float* __restrict__ b,
           const float* __restrict__ c, ushort* __restrict__ dst) {
    int i = (blockIdx.x * 256 + threadIdx.x) * 4;
    const float* src; int off;
    if (i < 262144)      { src = a; off = i; }
    else if (i < 524288) { src = b; off = i - 262144; }
    else                 { src = c; off = i - 524288; }
    float4 v = *(const float4*)(src + off);
    ushort4 o;
    o.x = f2bf(v.x); o.y = f2bf(v.y); o.z = f2bf(v.z); o.w = f2bf(v.w);
    *(ushort4*)(dst + i) = o;
}

// ---------------- C[m][n] = sum_k A[m][k] * B[n][k], bf16 in/out, fp32 acc ----
__global__ __launch_bounds__(256, 2)
void gemm_bt(const ushort* __restrict__ A, const ushort* __restrict__ B,
             ushort* __restrict__ C, int M, int N, int K)
{
    __shared__ ushort As[128][40];
    __shared__ ushort Bs[128][40];
    const int tid = threadIdx.x;
    const int lane = tid & 63, wave = tid >> 6;
    const int wm = wave >> 1, wn = wave & 1;
    const int lr = lane & 15, lq = lane >> 4;
    const int mBase = blockIdx.y * 128, nBase = blockIdx.x * 128;

    f32x4 acc[4][4];
    #pragma unroll
    for (int i = 0; i < 4; ++i)
        #pragma unroll
        for (int j = 0; j < 4; ++j) acc[i][j] = (f32x4){0.f, 0.f, 0.f, 0.f};

    for (int k0 = 0; k0 < K; k0 += 32) {
        __syncthreads();
        #pragma unroll
        for (int i = 0; i < 2; ++i) {
            int off = i * 4096 + tid * 16;
            int row = off >> 6, col = off & 63;
            *(uint4*)((char*)As + row * 80 + col) =
                *(const uint4*)((const char*)A + ((size_t)(mBase + row) * K + k0) * 2 + col);
            *(uint4*)((char*)Bs + row * 80 + col) =
                *(const uint4*)((const char*)B + ((size_t)(nBase + row) * K + k0) * 2 + col);
        }
        __syncthreads();
        bf16x8 af[4], bfr[4];
        #pragma unroll
        for (int mi = 0; mi < 4; ++mi) af[mi] = *(const bf16x8*)&As[wm * 64 + mi * 16 + lr][lq * 8];
        #pragma unroll
        for (int ni = 0; ni < 4; ++ni) bfr[ni] = *(const bf16x8*)&Bs[wn * 64 + ni * 16 + lr][lq * 8];
        #pragma unroll
        for (int mi = 0; mi < 4; ++mi)
            #pragma unroll
            for (int ni = 0; ni < 4; ++ni)
                acc[mi][ni] = __builtin_amdgcn_mfma_f32_16x16x32_bf16(af[mi], bfr[ni], acc[mi][ni], 0, 0, 0);
    }
    #pragma unroll
    for (int mi = 0; mi < 4; ++mi)
        #pragma unroll
        for (int ni = 0; ni < 4; ++ni)
            #pragma unroll
            for (int r = 0; r < 4; ++r) {
                int m = mBase + wm * 64 + mi * 16 + lq * 4 + r;
                int n = nBase + wn * 64 + ni * 16 + lr;
                C[(size_t)m * N + n] = f2bf(acc[mi][ni][r]);
            }
}

// ---------------- flash attention: split-S, static-max, ONE barrier/tile ----
// QK: [B*S][1024] bf16 (col 0..511 = Q, 512..1023 = K). Vt: [512][B*S] bf16.
// Grid (32, 8, 2). 32-key tiles, double-buffered K DMA with full-iteration
// in-flight window (single __syncthreads per tile). P is wave-private
// (same-wave LDS round-trip, no barrier). V B-frags loaded DIRECTLY from
// global in MFMA layout (16B/lane contiguous; 4 waves share via L1/L2).
__global__ __launch_bounds__(256, 2)
void attn_kernel(const ushort* __restrict__ QKg, const ushort* __restrict__ Vtg,
                 const int* __restrict__ maskg,
                 ushort* __restrict__ Pog, float* __restrict__ Mlg)
{
    const int S = 2048;
    const float SL2E = 0.0637587160f;  // (1/sqrt(512)) * log2(e)

    __shared__ ushort Ks[2][32][548]; // dbuf; row stride 1096B = 274 dw == 18 mod 32
    __shared__ ushort Ps[4][16][36];  // wave-private P 16 rows x 32 keys

    const int b = blockIdx.y, qt = blockIdx.x, half = blockIdx.z;
    const int tid = threadIdx.x, lane = tid & 63, wave = tid >> 6;
    const int lr = lane & 15, lq = lane >> 4;

    // resident Q fragments (QK row stride 1024 ush, Q at col 0)
    const ushort* Qp = QKg + ((size_t)b * S + qt * 64 + wave * 16 + lr) * 1024;
    bf16x8 qf[16];
    #pragma unroll
    for (int c = 0; c < 16; ++c) qf[c] = *(const bf16x8*)(Qp + c * 32 + lq * 8);

    f32x4 o[32];
    #pragma unroll
    for (int i = 0; i < 32; ++i) o[i] = (f32x4){0.f, 0.f, 0.f, 0.f};
    float l_i[4] = {0.f, 0.f, 0.f, 0.f};

    const char* Khalf = (const char*)(QKg + ((size_t)b * S + half * 1024) * 1024 + 512);
    const int* mrow = maskg + b * S + half * 1024;
    // V base for this (b, half); B-frag lane address: row d = db*16+lr,
    // cols key0 + lq*8 .. +7 (16 B contiguous; 4 lq-lanes = one 64B line)
    const ushort* Vbase = Vtg + (size_t)lr * 16384 + (size_t)b * 2048 + half * 1024 + lq * 8;

    // prologue: DMA tile 0 into Ks[0] (8 rows per wave, one 1024B row per instr)
    #pragma unroll
    for (int i = 0; i < 8; ++i) {
        int row = wave * 8 + i;
        async_copy16(&Ks[0][row][0], Khalf + (size_t)row * 2048 + lane * 16);
    }

    for (int kt = 0; kt < 32; ++kt) {
        const int key0 = kt * 32;
        const int cur = kt & 1;
        __syncthreads();  // drains DMA(kt) — covered by prev iteration's full body;
                          // Ks[cur] valid, Ks[cur^1] free (its readers ran in kt-1)
        // issue DMA(kt+1): in flight across QK + softmax + PV until next barrier
        if (kt < 31) {
            const char* gK = Khalf + (size_t)(key0 + 32) * 2048;
            #pragma unroll
            for (int i = 0; i < 8; ++i) {
                int row = wave * 8 + i;
                async_copy16(&Ks[cur ^ 1][row][0], gK + (size_t)row * 2048 + lane * 16);
            }
        }
        const bool msk0 = mrow[key0 + lr] != 0;
        const bool msk1 = mrow[key0 + 16 + lr] != 0;
        // S = Q Ktile^T (32 keys): 32 mfma 16x16x32
        f32x4 sf0 = (f32x4){0.f,0.f,0.f,0.f}, sf1 = (f32x4){0.f,0.f,0.f,0.f};
        #pragma unroll
        for (int ks = 0; ks < 16; ++ks) {
            bf16x8 kf0 = *(const bf16x8*)&Ks[cur][lr][ks * 32 + lq * 8];
            bf16x8 kf1 = *(const bf16x8*)&Ks[cur][16 + lr][ks * 32 + lq * 8];
            sf0 = __builtin_amdgcn_mfma_f32_16x16x32_bf16(qf[ks], kf0, sf0, 0, 0, 0);
            sf1 = __builtin_amdgcn_mfma_f32_16x16x32_bf16(qf[ks], kf1, sf1, 0, 0, 0);
        }
        // static-max softmax: p = exp2(score*SL2E - 8); l lane-local
        #pragma unroll
        for (int r = 0; r < 4; ++r) {
            float p0 = msk0 ? 0.f : exp2f(fmaf(sf0[r], SL2E, -8.f));
            float p1 = msk1 ? 0.f : exp2f(fmaf(sf1[r], SL2E, -8.f));
            l_i[r] += p0 + p1;
            Ps[wave][lq * 4 + r][lr]      = f2bf(p0);
            Ps[wave][lq * 4 + r][16 + lr] = f2bf(p1);
        }
        // P A-frag: k = lq*8+j covers all 32 keys (one frag per tile).
        // Same-wave LDS round-trip: compiler inserts lgkmcnt wait, no barrier.
        bf16x8 pf = *(const bf16x8*)&Ps[wave][lr][lq * 8];
        // O += P @ V, V B-frags straight from global (L1/L2-shared across waves)
        const ushort* Vp = Vbase + (size_t)key0;
        #pragma unroll
        for (int db = 0; db < 32; ++db) {
            bf16x8 vf = *(const bf16x8*)(Vp + (size_t)db * 16 * 16384);
            o[db] = __builtin_amdgcn_mfma_f32_16x16x32_bf16(pf, vf, o[db], 0, 0, 0);
        }
    }
    // final cross-lane l reduction (keys were distributed over 16 lr lanes)
    #pragma unroll
    for (int r = 0; r < 4; ++r)
        #pragma unroll
        for (int off = 1; off < 16; off <<= 1)
            l_i[r] += __shfl_xor(l_i[r], off, 16);
    // write unnormalized partial O (bf16) + l per row
    const size_t growbase = (size_t)half * 16384 + (size_t)b * S + qt * 64 + wave * 16;
    ushort* Pop = Pog + (growbase + lq * 4) * 512;
    #pragma unroll
    for (int db = 0; db < 32; ++db)
        #pragma unroll
        for (int r = 0; r < 4; ++r)
            Pop[(size_t)r * 512 + db * 16 + lr] = f2bf(o[db][r]);
    if (lr == 0) {
        #pragma unroll
        for (int r = 0; r < 4; ++r)
            Mlg[growbase + lq * 4 + r] = l_i[r];
    }
}

// ---------------- combine the two key-halves (shared static max) -------------
__global__ __launch_bounds__(256)
void combine_kernel(const ushort* __restrict__ Po, const float* __restrict__ Ml,
                    float* __restrict__ out)
{
    int i = (blockIdx.x * 256 + threadIdx.x) * 4;
    int row = i >> 9;
    float l = Ml[row] + Ml[16384 + row];
    float s = l > 0.f ? 1.f / l : 0.f;
    ushort4 p1 = *(const ushort4*)(Po + i);
    ushort4 p2 = *(const ushort4*)(Po + 8388608 + i);
    float4 o;
    o.x = (bf2f(p1.x) + bf2f(p2.x)) * s;
    o.y = (bf2f(p1.y) + bf2f(p2.y)) * s;
    o.z = (bf2f(p1.z) + bf2f(p2.z)) * s;
    o.w = (bf2f(p1.w) + bf2f(p2.w)) * s;
    *(float4*)(out + i) = o;
}

extern "C" void kernel_launch(void* const* d_in, const int* in_sizes, int n_in,
                              void* d_out, int out_size, void* d_ws, size_t ws_size,
                              hipStream_t stream) {
    const float* x  = (const float*)d_in[0];
    // d_in[1] = bias: additive scalar on all logits -> softmax shift-invariant -> no-op
    const int* mask = (const int*)d_in[2];
    const float* Wq = (const float*)d_in[3];
    const float* Wk = (const float*)d_in[4];
    const float* Wv = (const float*)d_in[5];
    float* out = (float*)d_out;

    // Workspace (ushort units). Region [0, 16777216) time-shared:
    //   phase 1: xb (8388608) + W-stack wq|wk|wv (786432)
    //   phase 2: Po (2 x 8388608 bf16 partial O)
    ushort* ws  = (ushort*)d_ws;
    ushort* xb  = ws;
    ushort* wst = ws + 8388608;            // Wq|Wk|Wv stacked (1536 x 512)
    ushort* Pob = ws;
    ushort* QKb = ws + 16777216;           // 16384 x 1024  ([Q|K] per row)
    ushort* Vtb = ws + 33554432;           // 512 x 16384   (V transposed)
    float*  Mlb = (float*)(ws + 41943040); // 32768 floats

    cvt_f32_bf16<<<8192, 256, 0, stream>>>(x, xb, 8388608);
    cvt_w<<<768, 256, 0, stream>>>(Wq, Wk, Wv, wst);
    // [Q|K] = x [Wq;Wk]^T  (M=16384, N=1024, K=512)
    gemm_bt<<<dim3(8, 128), 256, 0, stream>>>(xb, wst, QKb, 16384, 1024, 512);
    // Vt = Wv x^T  (M=512, N=16384, K=512)
    gemm_bt<<<dim3(128, 4), 256, 0, stream>>>(wst + 524288, xb, Vtb, 512, 16384, 512);
    attn_kernel<<<dim3(32, 8, 2), 256, 0, stream>>>(QKb, Vtb, mask, Pob, Mlb);
    combine_kernel<<<8192, 256, 0, stream>>>(Pob, Mlb, out);
}

// Round 7
// 251.312 us; speedup vs baseline: 1.8127x; 1.8127x over previous
//
#include <hip/hip_runtime.h>

typedef short bf16x8 __attribute__((ext_vector_type(8)));
typedef float f32x4 __attribute__((ext_vector_type(4)));
typedef float f32x16 __attribute__((ext_vector_type(16)));

__device__ __forceinline__ ushort f2bf(float f) {
    union { float f; unsigned u; } v; v.f = f;
    unsigned r = (v.u + 0x7fffu + ((v.u >> 16) & 1u)) >> 16;
    return (ushort)r;
}
__device__ __forceinline__ float bf2f(ushort u) {
    union { unsigned u; float f; } v; v.u = ((unsigned)u) << 16;
    return v.f;
}
__device__ __forceinline__ void async_copy16(void* lds, const void* g) {
    __builtin_amdgcn_global_load_lds(
        (const __attribute__((address_space(1))) unsigned*)g,
        (__attribute__((address_space(3))) unsigned*)lds, 16, 0, 0);
}

// ---------------- fp32 -> bf16 conversion ----------------
__global__ __launch_bounds__(256)
void cvt_f32_bf16(const float* __restrict__ src, ushort* __restrict__ dst, int n) {
    int i = (blockIdx.x * 256 + threadIdx.x) * 4;
    if (i >= n) return;
    float4 v = *(const float4*)(src + i);
    ushort4 o;
    o.x = f2bf(v.x); o.y = f2bf(v.y); o.z = f2bf(v.z); o.w = f2bf(v.w);
    *(ushort4*)(dst + i) = o;
}

// fused weight conversion: Wq|Wk|Wv (3 x 262144) -> contiguous bf16 stack
__global__ __launch_bounds__(256)
void cvt_w(const float* __restrict__ a, const float* __restrict__ b,
           const float* __restrict__ c, ushort* __restrict__ dst) {
    int i = (blockIdx.x * 256 + threadIdx.x) * 4;
    const float* src; int off;
    if (i < 262144)      { src = a; off = i; }
    else if (i < 524288) { src = b; off = i - 262144; }
    else                 { src = c; off = i - 524288; }
    float4 v = *(const float4*)(src + off);
    ushort4 o;
    o.x = f2bf(v.x); o.y = f2bf(v.y); o.z = f2bf(v.z); o.w = f2bf(v.w);
    *(ushort4*)(dst + i) = o;
}

// ---------------- mask compaction: per (b,half) list of unmasked keys --------
// grid 16 blocks = seg (b*2+half), 256 threads, 1024 keys/segment, 4 keys/thread
__global__ __launch_bounds__(256)
void compact_mask(const int* __restrict__ mask, int* __restrict__ idx,
                  int* __restrict__ cnt)
{
    int seg = blockIdx.x, b = seg >> 1, half = seg & 1;
    const int* m = mask + b * 2048 + half * 1024;
    int t = threadIdx.x;
    __shared__ int sc[256];
    int v0 = (m[t*4+0] == 0), v1 = (m[t*4+1] == 0);
    int v2 = (m[t*4+2] == 0), v3 = (m[t*4+3] == 0);
    int c = v0 + v1 + v2 + v3;
    sc[t] = c; __syncthreads();
    for (int ofs = 1; ofs < 256; ofs <<= 1) {   // Hillis-Steele inclusive scan
        int x = (t >= ofs) ? sc[t - ofs] : 0;
        __syncthreads(); sc[t] += x; __syncthreads();
    }
    int pos = sc[t] - c + seg * 1024;           // exclusive prefix + seg base
    if (v0) idx[pos++] = t*4+0;
    if (v1) idx[pos++] = t*4+1;
    if (v2) idx[pos++] = t*4+2;
    if (v3) idx[pos++] = t*4+3;
    if (t == 255) cnt[seg] = sc[255];
}

// ---------------- gather unmasked x-rows, zero-pad to capacity 1024/seg ------
// grid (16, 16): seg x 64-row block; each wave copies 16 rows (1 KB = 64x16B)
__global__ __launch_bounds__(256)
void gather_rows(const ushort* __restrict__ xb, const int* __restrict__ idx,
                 const int* __restrict__ cnt, ushort* __restrict__ xc)
{
    int seg = blockIdx.x, b = seg >> 1, half = seg & 1;
    int n = cnt[seg];
    int wave = threadIdx.x >> 6, lane = threadIdx.x & 63;
    int j0 = blockIdx.y * 64 + wave * 16;
    for (int i = 0; i < 16; ++i) {
        int j = j0 + i;
        uint4 val = {0u, 0u, 0u, 0u};
        if (j < n) {
            int src = idx[seg * 1024 + j];
            val = *(const uint4*)((const char*)xb +
                  ((size_t)(b * 2048 + half * 1024 + src)) * 1024 + lane * 16);
        }
        *(uint4*)((char*)xc + ((size_t)(seg * 1024 + j)) * 1024 + lane * 16) = val;
    }
}

// ---------------- C[m][n] = sum_k A[m][k] * B[n][k], bf16 in/out, fp32 acc ----
// Optional per-1024-segment early-exit on M (cntM) or N (cntN) pad bands.
__global__ __launch_bounds__(256, 2)
void gemm_bt(const ushort* __restrict__ A, const ushort* __restrict__ B,
             ushort* __restrict__ C, int M, int N, int K,
             const int* __restrict__ cntM, const int* __restrict__ cntN)
{
    const int mBase = blockIdx.y * 128, nBase = blockIdx.x * 128;
    if (cntM && (mBase & 1023) >= cntM[mBase >> 10]) return;
    if (cntN && (nBase & 1023) >= cntN[nBase >> 10]) return;

    __shared__ ushort As[128][40];
    __shared__ ushort Bs[128][40];
    const int tid = threadIdx.x;
    const int lane = tid & 63, wave = tid >> 6;
    const int wm = wave >> 1, wn = wave & 1;
    const int lr = lane & 15, lq = lane >> 4;

    f32x4 acc[4][4];
    #pragma unroll
    for (int i = 0; i < 4; ++i)
        #pragma unroll
        for (int j = 0; j < 4; ++j) acc[i][j] = (f32x4){0.f, 0.f, 0.f, 0.f};

    for (int k0 = 0; k0 < K; k0 += 32) {
        __syncthreads();
        #pragma unroll
        for (int i = 0; i < 2; ++i) {
            int off = i * 4096 + tid * 16;
            int row = off >> 6, col = off & 63;
            *(uint4*)((char*)As + row * 80 + col) =
                *(const uint4*)((const char*)A + ((size_t)(mBase + row) * K + k0) * 2 + col);
            *(uint4*)((char*)Bs + row * 80 + col) =
                *(const uint4*)((const char*)B + ((size_t)(nBase + row) * K + k0) * 2 + col);
        }
        __syncthreads();
        bf16x8 af[4], bfr[4];
        #pragma unroll
        for (int mi = 0; mi < 4; ++mi) af[mi] = *(const bf16x8*)&As[wm * 64 + mi * 16 + lr][lq * 8];
        #pragma unroll
        for (int ni = 0; ni < 4; ++ni) bfr[ni] = *(const bf16x8*)&Bs[wn * 64 + ni * 16 + lr][lq * 8];
        #pragma unroll
        for (int mi = 0; mi < 4; ++mi)
            #pragma unroll
            for (int ni = 0; ni < 4; ++ni)
                acc[mi][ni] = __builtin_amdgcn_mfma_f32_16x16x32_bf16(af[mi], bfr[ni], acc[mi][ni], 0, 0, 0);
    }
    #pragma unroll
    for (int mi = 0; mi < 4; ++mi)
        #pragma unroll
        for (int ni = 0; ni < 4; ++ni)
            #pragma unroll
            for (int r = 0; r < 4; ++r) {
                int m = mBase + wm * 64 + mi * 16 + lq * 4 + r;
                int n = nBase + wn * 64 + ni * 16 + lr;
                C[(size_t)m * N + n] = f2bf(acc[mi][ni][r]);
            }
}

// ---------------- flash attention over COMPACTED keys ------------------------
// Q: [B*S][512]. Kc: [16 segs][1024 rows][512] (rows < cnt valid, pads zero).
// Vtc: [512][16 segs * 1024] (cols < cnt valid, pads zero).
// Grid (32, 8, 2): 64 q-rows x seg(b,half). ntiles = ceil(cnt/32) ~ 17 vs 32.
// R4 structure: 32-key tiles, pair-split PV (mfma 32x32x16), static-max.
__global__ __launch_bounds__(256, 2)
void attn_kernel(const ushort* __restrict__ Qg, const ushort* __restrict__ Kcg,
                 const ushort* __restrict__ Vtcg, const int* __restrict__ cntg,
                 ushort* __restrict__ Pog, float* __restrict__ Mlg)
{
    const int S = 2048;
    const float SL2E = 0.0637587160f;  // (1/sqrt(512)) * log2(e)

    __shared__ ushort Ks[32][548];   // stride 1096B = 274 dw == 18 mod 32
    __shared__ ushort Vs[512][36];   // stride 72B = 18 dw (2-way, free)
    __shared__ ushort Ps[2][32][36]; // per-pair P 32 rows x 32 keys

    const int b = blockIdx.y, qt = blockIdx.x, half = blockIdx.z;
    const int seg = b * 2 + half;
    const int tid = threadIdx.x, lane = tid & 63, wave = tid >> 6;
    const int lr = lane & 15, lq = lane >> 4;
    const int p = wave >> 1, s = wave & 1;
    const int l32 = lane & 31, lh = lane >> 5;

    const int n = cntg[seg];
    const int ntiles = (n + 31) >> 5;

    const ushort* Qp = Qg + ((size_t)b * S + qt * 64 + wave * 16 + lr) * 512;
    bf16x8 qf[16];
    #pragma unroll
    for (int c = 0; c < 16; ++c) qf[c] = *(const bf16x8*)(Qp + c * 32 + lq * 8);

    f32x16 o[8];
    #pragma unroll
    for (int i = 0; i < 8; ++i)
        #pragma unroll
        for (int r = 0; r < 16; ++r) o[i][r] = 0.f;
    float l_i[4] = {0.f, 0.f, 0.f, 0.f};

    const char* Kseg = (const char*)(Kcg + (size_t)seg * 1024 * 512);
    const char* Vseg = (const char*)Vtcg + (size_t)(seg * 1024) * 2;  // row stride 32768 B

    for (int kt = 0; kt < ntiles; ++kt) {
        const int key0 = kt * 32;
        __syncthreads();   // prev tile fully consumed (Ks/Vs/Ps)
        {   // K tile DMA: one 1024B compacted row per instruction
            const char* gK = Kseg + (size_t)key0 * 1024;
            #pragma unroll
            for (int i = 0; i < 8; ++i) {
                int row = wave * 8 + i;
                async_copy16(&Ks[row][0], gK + (size_t)row * 1024 + lane * 16);
            }
        }
        const bool va0 = (key0 + lr) < n;        // pad-key predicate (replaces mask)
        const bool va1 = (key0 + 16 + lr) < n;
        __syncthreads();   // drains K DMA -> Ks valid
        // V prefetch into regs; consumed after QK+softmax (latency hidden)
        uint4 vreg[8];
        {
            const char* gV = Vseg + (size_t)key0 * 2;
            #pragma unroll
            for (int i = 0; i < 8; ++i) {
                int off = i * 4096 + tid * 16;
                int row = off >> 6, col = off & 63;
                vreg[i] = *(const uint4*)(gV + (size_t)row * 32768 + col);
            }
        }
        // S = Q Ktile^T (16x16x32)
        f32x4 sf0 = (f32x4){0.f,0.f,0.f,0.f}, sf1 = (f32x4){0.f,0.f,0.f,0.f};
        #pragma unroll
        for (int ks = 0; ks < 16; ++ks) {
            bf16x8 kf0 = *(const bf16x8*)&Ks[lr][ks * 32 + lq * 8];
            bf16x8 kf1 = *(const bf16x8*)&Ks[16 + lr][ks * 32 + lq * 8];
            sf0 = __builtin_amdgcn_mfma_f32_16x16x32_bf16(qf[ks], kf0, sf0, 0, 0, 0);
            sf1 = __builtin_amdgcn_mfma_f32_16x16x32_bf16(qf[ks], kf1, sf1, 0, 0, 0);
        }
        // static-max softmax: p = exp2(score*SL2E - 8); l lane-local
        #pragma unroll
        for (int r = 0; r < 4; ++r) {
            float p0 = va0 ? exp2f(fmaf(sf0[r], SL2E, -8.f)) : 0.f;
            float p1 = va1 ? exp2f(fmaf(sf1[r], SL2E, -8.f)) : 0.f;
            l_i[r] += p0 + p1;
            Ps[p][16 * s + lq * 4 + r][lr]      = f2bf(p0);
            Ps[p][16 * s + lq * 4 + r][16 + lr] = f2bf(p1);
        }
        // V regs -> LDS
        #pragma unroll
        for (int i = 0; i < 8; ++i) {
            int off = i * 4096 + tid * 16;
            int row = off >> 6, col = off & 63;
            *(uint4*)((char*)Vs + row * 72 + col) = vreg[i];
        }
        __syncthreads();   // P (cross-wave within pair) + V visible
        // O += P(32x32) @ V(32 x d256) via mfma 32x32x16, d-range by s
        bf16x8 pA0 = *(const bf16x8*)&Ps[p][l32][lh * 8];
        bf16x8 pA1 = *(const bf16x8*)&Ps[p][l32][16 + lh * 8];
        #pragma unroll
        for (int dt = 0; dt < 8; ++dt) {
            int d = s * 256 + dt * 32 + l32;
            bf16x8 v0 = *(const bf16x8*)&Vs[d][lh * 8];
            bf16x8 v1 = *(const bf16x8*)&Vs[d][16 + lh * 8];
            o[dt] = __builtin_amdgcn_mfma_f32_32x32x16_bf16(pA0, v0, o[dt], 0, 0, 0);
            o[dt] = __builtin_amdgcn_mfma_f32_32x32x16_bf16(pA1, v1, o[dt], 0, 0, 0);
        }
    }
    // final cross-lane l reduction (QK-wave owns rows 16w..16w+16)
    #pragma unroll
    for (int r = 0; r < 4; ++r)
        #pragma unroll
        for (int off = 1; off < 16; off <<= 1)
            l_i[r] += __shfl_xor(l_i[r], off, 16);
    const size_t growbase = (size_t)half * 16384 + (size_t)b * S + qt * 64;
    if (lr == 0) {
        #pragma unroll
        for (int r = 0; r < 4; ++r)
            Mlg[growbase + wave * 16 + lq * 4 + r] = l_i[r];
    }
    // write unnormalized partial O: pair rows [32p,32p+32), cols [256s,256s+256)
    // 32x32 C-layout: col = lane&31, row = (r&3) + 8*(r>>2) + 4*(lane>>5)
    ushort* Pop = Pog + (growbase + p * 32) * 512;
    #pragma unroll
    for (int dt = 0; dt < 8; ++dt) {
        int ocol = s * 256 + dt * 32 + l32;
        #pragma unroll
        for (int r = 0; r < 16; ++r) {
            int orow = (r & 3) + 8 * (r >> 2) + 4 * lh;
            Pop[(size_t)orow * 512 + ocol] = f2bf(o[dt][r]);
        }
    }
}

// ---------------- combine the two key-halves (shared static max) -------------
__global__ __launch_bounds__(256)
void combine_kernel(const ushort* __restrict__ Po, const float* __restrict__ Ml,
                    float* __restrict__ out)
{
    int i = (blockIdx.x * 256 + threadIdx.x) * 4;
    int row = i >> 9;
    float l = Ml[row] + Ml[16384 + row];
    float s = l > 0.f ? 1.f / l : 0.f;
    ushort4 p1 = *(const ushort4*)(Po + i);
    ushort4 p2 = *(const ushort4*)(Po + 8388608 + i);
    float4 o;
    o.x = (bf2f(p1.x) + bf2f(p2.x)) * s;
    o.y = (bf2f(p1.y) + bf2f(p2.y)) * s;
    o.z = (bf2f(p1.z) + bf2f(p2.z)) * s;
    o.w = (bf2f(p1.w) + bf2f(p2.w)) * s;
    *(float4*)(out + i) = o;
}

extern "C" void kernel_launch(void* const* d_in, const int* in_sizes, int n_in,
                              void* d_out, int out_size, void* d_ws, size_t ws_size,
                              hipStream_t stream) {
    const float* x  = (const float*)d_in[0];
    // d_in[1] = bias: additive scalar on all logits -> softmax shift-invariant -> no-op
    const int* mask = (const int*)d_in[2];
    const float* Wq = (const float*)d_in[3];
    const float* Wk = (const float*)d_in[4];
    const float* Wv = (const float*)d_in[5];
    float* out = (float*)d_out;

    // Workspace (ushort units). Phase 1: xb|wst|xc @ [0, 17563648); idx overlaps
    // the Qb region (dead before gemm Q). Phase 2: Pob overlaps [0, 16777216).
    ushort* ws   = (ushort*)d_ws;
    ushort* xb   = ws;                         // 16384 x 512
    ushort* wst  = ws + 8388608;               // Wq|Wk|Wv (1536 x 512)
    ushort* xc   = ws + 9175040;               // 16 segs x 1024 x 512 (gathered, padded)
    ushort* Pob  = ws;                         // phase 2: 2 x 8388608
    ushort* Qb   = ws + 17563648;              // 16384 x 512
    int*    idxb = (int*)Qb;                   // 16384 ints (dead before gemm Q)
    ushort* Kc   = ws + 25952256;              // 16 segs x 1024 x 512
    ushort* Vtc  = ws + 34340864;              // 512 x 16384
    float*  Mlb  = (float*)(ws + 42729472);    // 32768 floats
    int*    cntb = (int*)(ws + 42795008);      // 16 ints

    cvt_f32_bf16<<<8192, 256, 0, stream>>>(x, xb, 8388608);
    cvt_w<<<768, 256, 0, stream>>>(Wq, Wk, Wv, wst);
    compact_mask<<<16, 256, 0, stream>>>(mask, idxb, cntb);
    gather_rows<<<dim3(16, 16), 256, 0, stream>>>(xb, idxb, cntb, xc);
    // Q = x Wq^T (full)
    gemm_bt<<<dim3(4, 128), 256, 0, stream>>>(xb, wst, Qb, 16384, 512, 512, nullptr, nullptr);
    // Kc = xc Wk^T (skip all-pad M bands)
    gemm_bt<<<dim3(4, 128), 256, 0, stream>>>(xc, wst + 262144, Kc, 16384, 512, 512, cntb, nullptr);
    // Vtc = Wv xc^T (skip all-pad N bands)
    gemm_bt<<<dim3(128, 4), 256, 0, stream>>>(wst + 524288, xc, Vtc, 512, 16384, 512, nullptr, cntb);
    attn_kernel<<<dim3(32, 8, 2), 256, 0, stream>>>(Qb, Kc, Vtc, cntb, Pob, Mlb);
    combine_kernel<<<8192, 256, 0, stream>>>(Pob, Mlb, out);
}

// Round 8
// 242.252 us; speedup vs baseline: 1.8805x; 1.0374x over previous
//
#include <hip/hip_runtime.h>

typedef short bf16x8 __attribute__((ext_vector_type(8)));
typedef float f32x4 __attribute__((ext_vector_type(4)));
typedef float f32x16 __attribute__((ext_vector_type(16)));

__device__ __forceinline__ ushort f2bf(float f) {
    union { float f; unsigned u; } v; v.f = f;
    unsigned r = (v.u + 0x7fffu + ((v.u >> 16) & 1u)) >> 16;
    return (ushort)r;
}
__device__ __forceinline__ float bf2f(ushort u) {
    union { unsigned u; float f; } v; v.u = ((unsigned)u) << 16;
    return v.f;
}
__device__ __forceinline__ void async_copy16(void* lds, const void* g) {
    __builtin_amdgcn_global_load_lds(
        (const __attribute__((address_space(1))) unsigned*)g,
        (__attribute__((address_space(3))) unsigned*)lds, 16, 0, 0);
}

// ---------------- fp32 -> bf16 conversion ----------------
__global__ __launch_bounds__(256)
void cvt_f32_bf16(const float* __restrict__ src, ushort* __restrict__ dst, int n) {
    int i = (blockIdx.x * 256 + threadIdx.x) * 4;
    if (i >= n) return;
    float4 v = *(const float4*)(src + i);
    ushort4 o;
    o.x = f2bf(v.x); o.y = f2bf(v.y); o.z = f2bf(v.z); o.w = f2bf(v.w);
    *(ushort4*)(dst + i) = o;
}

// ---------------- transpose-convert 512x512 fp32 -> bf16 (out[c][r]=in[r][c])
// grid (8,8,2): z selects (Wq->WqT) or (Wk->WkT)
__global__ __launch_bounds__(256)
void cvt_wT(const float* __restrict__ in0, const float* __restrict__ in1,
            ushort* __restrict__ out0, ushort* __restrict__ out1)
{
    const float* in = blockIdx.z ? in1 : in0;
    ushort* out     = blockIdx.z ? out1 : out0;
    __shared__ ushort T[64][72];
    const int r0 = blockIdx.y * 64, c0 = blockIdx.x * 64;
    const int t = threadIdx.x;
    const int rr = t >> 3, cc8 = (t & 7) * 8;
    #pragma unroll
    for (int pass = 0; pass < 2; ++pass) {
        int r = rr + pass * 32;
        float4 a = *(const float4*)(in + (size_t)(r0 + r) * 512 + c0 + cc8);
        float4 bq = *(const float4*)(in + (size_t)(r0 + r) * 512 + c0 + cc8 + 4);
        T[r][cc8+0]=f2bf(a.x);  T[r][cc8+1]=f2bf(a.y);  T[r][cc8+2]=f2bf(a.z);  T[r][cc8+3]=f2bf(a.w);
        T[r][cc8+4]=f2bf(bq.x); T[r][cc8+5]=f2bf(bq.y); T[r][cc8+6]=f2bf(bq.z); T[r][cc8+7]=f2bf(bq.w);
    }
    __syncthreads();
    const int c = t >> 2, seg = (t & 3) * 16;
    ushort tmp[16];
    #pragma unroll
    for (int j = 0; j < 16; ++j) tmp[j] = T[seg + j][c];
    *(uint4*)(out + (size_t)(c0 + c) * 512 + r0 + seg)     = *(uint4*)&tmp[0];
    *(uint4*)(out + (size_t)(c0 + c) * 512 + r0 + seg + 8) = *(uint4*)&tmp[8];
}

// ---------------- mask compaction: per (b,half) list of unmasked keys --------
__global__ __launch_bounds__(256)
void compact_mask(const int* __restrict__ mask, int* __restrict__ idx,
                  int* __restrict__ cnt)
{
    int seg = blockIdx.x, b = seg >> 1, half = seg & 1;
    const int* m = mask + b * 2048 + half * 1024;
    int t = threadIdx.x;
    __shared__ int sc[256];
    int v0 = (m[t*4+0] == 0), v1 = (m[t*4+1] == 0);
    int v2 = (m[t*4+2] == 0), v3 = (m[t*4+3] == 0);
    int c = v0 + v1 + v2 + v3;
    sc[t] = c; __syncthreads();
    for (int ofs = 1; ofs < 256; ofs <<= 1) {
        int x = (t >= ofs) ? sc[t - ofs] : 0;
        __syncthreads(); sc[t] += x; __syncthreads();
    }
    int pos = sc[t] - c + seg * 1024;
    if (v0) idx[pos++] = t*4+0;
    if (v1) idx[pos++] = t*4+1;
    if (v2) idx[pos++] = t*4+2;
    if (v3) idx[pos++] = t*4+3;
    if (t == 255) cnt[seg] = sc[255];
}

// ---------------- gather unmasked x-rows, zero-pad to capacity 1024/seg ------
__global__ __launch_bounds__(256)
void gather_rows(const ushort* __restrict__ xb, const int* __restrict__ idx,
                 const int* __restrict__ cnt, ushort* __restrict__ xc)
{
    int seg = blockIdx.x, b = seg >> 1, half = seg & 1;
    int n = cnt[seg];
    int wave = threadIdx.x >> 6, lane = threadIdx.x & 63;
    int j0 = blockIdx.y * 64 + wave * 16;
    for (int i = 0; i < 16; ++i) {
        int j = j0 + i;
        uint4 val = {0u, 0u, 0u, 0u};
        if (j < n) {
            int src = idx[seg * 1024 + j];
            val = *(const uint4*)((const char*)xb +
                  ((size_t)(b * 2048 + half * 1024 + src)) * 1024 + lane * 16);
        }
        *(uint4*)((char*)xc + ((size_t)(seg * 1024 + j)) * 1024 + lane * 16) = val;
    }
}

// ---------------- C[m][n] = sum_k A[m][k] * B[n][k], bf16 in/out, fp32 acc ----
// m97-style: global_load_lds width-16 staging, unpadded LDS (verified: the
// frag-read pattern hits every bank exactly 8x per b128 -> no excess conflict).
// Optional per-1024-segment early-exit on M (cntM) or N (cntN) pad bands.
__global__ __launch_bounds__(256, 2)
void gemm_bt(const ushort* __restrict__ A, const ushort* __restrict__ B,
             ushort* __restrict__ C, int M, int N, int K,
             const int* __restrict__ cntM, const int* __restrict__ cntN)
{
    const int mBase = blockIdx.y * 128, nBase = blockIdx.x * 128;
    if (cntM && (mBase & 1023) >= cntM[mBase >> 10]) return;
    if (cntN && (nBase & 1023) >= cntN[nBase >> 10]) return;

    __shared__ ushort As[128][32];
    __shared__ ushort Bs[128][32];
    const int tid = threadIdx.x;
    const int lane = tid & 63, wave = tid >> 6;
    const int wm = wave >> 1, wn = wave & 1;
    const int lr = lane & 15, lq = lane >> 4;
    const int sr = lane >> 2;           // staging sub-row 0..15
    const int sc = (lane & 3) * 8;      // staging col (ushorts)

    f32x4 acc[4][4];
    #pragma unroll
    for (int i = 0; i < 4; ++i)
        #pragma unroll
        for (int j = 0; j < 4; ++j) acc[i][j] = (f32x4){0.f, 0.f, 0.f, 0.f};

    for (int k0 = 0; k0 < K; k0 += 32) {
        __syncthreads();
        #pragma unroll
        for (int j = 0; j < 2; ++j) {
            int rbase = wave * 32 + j * 16;
            async_copy16(&As[rbase][0], A + (size_t)(mBase + rbase + sr) * K + k0 + sc);
            async_copy16(&Bs[rbase][0], B + (size_t)(nBase + rbase + sr) * K + k0 + sc);
        }
        __syncthreads();
        bf16x8 af[4], bfr[4];
        #pragma unroll
        for (int mi = 0; mi < 4; ++mi) af[mi] = *(const bf16x8*)&As[wm * 64 + mi * 16 + lr][lq * 8];
        #pragma unroll
        for (int ni = 0; ni < 4; ++ni) bfr[ni] = *(const bf16x8*)&Bs[wn * 64 + ni * 16 + lr][lq * 8];
        #pragma unroll
        for (int mi = 0; mi < 4; ++mi)
            #pragma unroll
            for (int ni = 0; ni < 4; ++ni)
                acc[mi][ni] = __builtin_amdgcn_mfma_f32_16x16x32_bf16(af[mi], bfr[ni], acc[mi][ni], 0, 0, 0);
    }
    #pragma unroll
    for (int mi = 0; mi < 4; ++mi)
        #pragma unroll
        for (int ni = 0; ni < 4; ++ni)
            #pragma unroll
            for (int r = 0; r < 4; ++r) {
                int m = mBase + wm * 64 + mi * 16 + lq * 4 + r;
                int n = nBase + wn * 64 + ni * 16 + lr;
                C[(size_t)m * N + n] = f2bf(acc[mi][ni][r]);
            }
}

// ---------------- flash attention over COMPACTED keys (R7 structure) ---------
// Q = xb [B*S][512] (scores = x M xc^T -> Q is x itself). K'c: [16][1024][512].
// Vtc: [512][16*1024]. Grid (32,8,2). 32-key tiles, pair-split PV, static-max.
__global__ __launch_bounds__(256, 2)
void attn_kernel(const ushort* __restrict__ Qg, const ushort* __restrict__ Kcg,
                 const ushort* __restrict__ Vtcg, const int* __restrict__ cntg,
                 ushort* __restrict__ Pog, float* __restrict__ Mlg)
{
    const int S = 2048;
    const float SL2E = 0.0637587160f;  // (1/sqrt(512)) * log2(e)

    __shared__ ushort Ks[32][548];
    __shared__ ushort Vs[512][36];
    __shared__ ushort Ps[2][32][36];

    const int b = blockIdx.y, qt = blockIdx.x, half = blockIdx.z;
    const int seg = b * 2 + half;
    const int tid = threadIdx.x, lane = tid & 63, wave = tid >> 6;
    const int lr = lane & 15, lq = lane >> 4;
    const int p = wave >> 1, s = wave & 1;
    const int l32 = lane & 31, lh = lane >> 5;

    const int n = cntg[seg];
    const int ntiles = (n + 31) >> 5;

    const ushort* Qp = Qg + ((size_t)b * S + qt * 64 + wave * 16 + lr) * 512;
    bf16x8 qf[16];
    #pragma unroll
    for (int c = 0; c < 16; ++c) qf[c] = *(const bf16x8*)(Qp + c * 32 + lq * 8);

    f32x16 o[8];
    #pragma unroll
    for (int i = 0; i < 8; ++i)
        #pragma unroll
        for (int r = 0; r < 16; ++r) o[i][r] = 0.f;
    float l_i[4] = {0.f, 0.f, 0.f, 0.f};

    const char* Kseg = (const char*)(Kcg + (size_t)seg * 1024 * 512);
    const char* Vseg = (const char*)Vtcg + (size_t)(seg * 1024) * 2;

    for (int kt = 0; kt < ntiles; ++kt) {
        const int key0 = kt * 32;
        __syncthreads();
        {
            const char* gK = Kseg + (size_t)key0 * 1024;
            #pragma unroll
            for (int i = 0; i < 8; ++i) {
                int row = wave * 8 + i;
                async_copy16(&Ks[row][0], gK + (size_t)row * 1024 + lane * 16);
            }
        }
        const bool va0 = (key0 + lr) < n;
        const bool va1 = (key0 + 16 + lr) < n;
        __syncthreads();
        uint4 vreg[8];
        {
            const char* gV = Vseg + (size_t)key0 * 2;
            #pragma unroll
            for (int i = 0; i < 8; ++i) {
                int off = i * 4096 + tid * 16;
                int row = off >> 6, col = off & 63;
                vreg[i] = *(const uint4*)(gV + (size_t)row * 32768 + col);
            }
        }
        f32x4 sf0 = (f32x4){0.f,0.f,0.f,0.f}, sf1 = (f32x4){0.f,0.f,0.f,0.f};
        #pragma unroll
        for (int ks = 0; ks < 16; ++ks) {
            bf16x8 kf0 = *(const bf16x8*)&Ks[lr][ks * 32 + lq * 8];
            bf16x8 kf1 = *(const bf16x8*)&Ks[16 + lr][ks * 32 + lq * 8];
            sf0 = __builtin_amdgcn_mfma_f32_16x16x32_bf16(qf[ks], kf0, sf0, 0, 0, 0);
            sf1 = __builtin_amdgcn_mfma_f32_16x16x32_bf16(qf[ks], kf1, sf1, 0, 0, 0);
        }
        #pragma unroll
        for (int r = 0; r < 4; ++r) {
            float p0 = va0 ? exp2f(fmaf(sf0[r], SL2E, -8.f)) : 0.f;
            float p1 = va1 ? exp2f(fmaf(sf1[r], SL2E, -8.f)) : 0.f;
            l_i[r] += p0 + p1;
            Ps[p][16 * s + lq * 4 + r][lr]      = f2bf(p0);
            Ps[p][16 * s + lq * 4 + r][16 + lr] = f2bf(p1);
        }
        #pragma unroll
        for (int i = 0; i < 8; ++i) {
            int off = i * 4096 + tid * 16;
            int row = off >> 6, col = off & 63;
            *(uint4*)((char*)Vs + row * 72 + col) = vreg[i];
        }
        __syncthreads();
        bf16x8 pA0 = *(const bf16x8*)&Ps[p][l32][lh * 8];
        bf16x8 pA1 = *(const bf16x8*)&Ps[p][l32][16 + lh * 8];
        #pragma unroll
        for (int dt = 0; dt < 8; ++dt) {
            int d = s * 256 + dt * 32 + l32;
            bf16x8 v0 = *(const bf16x8*)&Vs[d][lh * 8];
            bf16x8 v1 = *(const bf16x8*)&Vs[d][16 + lh * 8];
            o[dt] = __builtin_amdgcn_mfma_f32_32x32x16_bf16(pA0, v0, o[dt], 0, 0, 0);
            o[dt] = __builtin_amdgcn_mfma_f32_32x32x16_bf16(pA1, v1, o[dt], 0, 0, 0);
        }
    }
    #pragma unroll
    for (int r = 0; r < 4; ++r)
        #pragma unroll
        for (int off = 1; off < 16; off <<= 1)
            l_i[r] += __shfl_xor(l_i[r], off, 16);
    const size_t growbase = (size_t)half * 16384 + (size_t)b * S + qt * 64;
    if (lr == 0) {
        #pragma unroll
        for (int r = 0; r < 4; ++r)
            Mlg[growbase + wave * 16 + lq * 4 + r] = l_i[r];
    }
    ushort* Pop = Pog + (growbase + p * 32) * 512;
    #pragma unroll
    for (int dt = 0; dt < 8; ++dt) {
        int ocol = s * 256 + dt * 32 + l32;
        #pragma unroll
        for (int r = 0; r < 16; ++r) {
            int orow = (r & 3) + 8 * (r >> 2) + 4 * lh;
            Pop[(size_t)orow * 512 + ocol] = f2bf(o[dt][r]);
        }
    }
}

// ---------------- combine the two key-halves (shared static max) -------------
__global__ __launch_bounds__(256)
void combine_kernel(const ushort* __restrict__ Po, const float* __restrict__ Ml,
                    float* __restrict__ out)
{
    int i = (blockIdx.x * 256 + threadIdx.x) * 4;
    int row = i >> 9;
    float l = Ml[row] + Ml[16384 + row];
    float s = l > 0.f ? 1.f / l : 0.f;
    ushort4 p1 = *(const ushort4*)(Po + i);
    ushort4 p2 = *(const ushort4*)(Po + 8388608 + i);
    float4 o;
    o.x = (bf2f(p1.x) + bf2f(p2.x)) * s;
    o.y = (bf2f(p1.y) + bf2f(p2.y)) * s;
    o.z = (bf2f(p1.z) + bf2f(p2.z)) * s;
    o.w = (bf2f(p1.w) + bf2f(p2.w)) * s;
    *(float4*)(out + i) = o;
}

extern "C" void kernel_launch(void* const* d_in, const int* in_sizes, int n_in,
                              void* d_out, int out_size, void* d_ws, size_t ws_size,
                              hipStream_t stream) {
    const float* x  = (const float*)d_in[0];
    // d_in[1] = bias: additive scalar on all logits -> softmax shift-invariant -> no-op
    const int* mask = (const int*)d_in[2];
    const float* Wq = (const float*)d_in[3];
    const float* Wk = (const float*)d_in[4];
    const float* Wv = (const float*)d_in[5];
    float* out = (float*)d_out;

    // Workspace (ushort units).
    //  xb  [0,        8388608)   bf16 x — live ALL phases (attn Q reads it)
    //  wst [8388608,  9175040)   WqT | WkT | Wv
    //  xc  [9175040, 17563648)   gathered rows (dead after gemms)
    //  Po  [9175040, 25952256)   phase 2 only (overlaps wst+xc+Mb+idx, all dead)
    //  Mb  [17563648,17825792)   M = Wq^T Wk (phase 1)
    //  idx [17825792,17858560)   compaction indices (phase 1)
    //  K'c [25952256,34340864)
    //  Vtc [34340864,42729472)
    //  Ml  [42729472,42795008)
    //  cnt [42795008,42795040)
    ushort* ws   = (ushort*)d_ws;
    ushort* xb   = ws;
    ushort* wqT  = ws + 8388608;
    ushort* wkT  = wqT + 262144;
    ushort* wvb  = wkT + 262144;
    ushort* xc   = ws + 9175040;
    ushort* Pob  = ws + 9175040;
    ushort* Mb   = ws + 17563648;
    int*    idxb = (int*)(ws + 17825792);
    ushort* Kc   = ws + 25952256;
    ushort* Vtc  = ws + 34340864;
    float*  Mlb  = (float*)(ws + 42729472);
    int*    cntb = (int*)(ws + 42795008);

    cvt_f32_bf16<<<8192, 256, 0, stream>>>(x, xb, 8388608);
    cvt_f32_bf16<<<256, 256, 0, stream>>>(Wv, wvb, 262144);
    cvt_wT<<<dim3(8, 8, 2), 256, 0, stream>>>(Wq, Wk, wqT, wkT);
    compact_mask<<<16, 256, 0, stream>>>(mask, idxb, cntb);
    gather_rows<<<dim3(16, 16), 256, 0, stream>>>(xb, idxb, cntb, xc);
    // M = Wq^T Wk: C[d][e] = sum_i WqT[d][i] * WkT[e][i]
    gemm_bt<<<dim3(4, 4), 256, 0, stream>>>(wqT, wkT, Mb, 512, 512, 512, nullptr, nullptr);
    // K'c = xc M^T (skip all-pad M bands)
    gemm_bt<<<dim3(4, 128), 256, 0, stream>>>(xc, Mb, Kc, 16384, 512, 512, cntb, nullptr);
    // Vtc = Wv xc^T (skip all-pad N bands)
    gemm_bt<<<dim3(128, 4), 256, 0, stream>>>(wvb, xc, Vtc, 512, 16384, 512, nullptr, cntb);
    attn_kernel<<<dim3(32, 8, 2), 256, 0, stream>>>(xb, Kc, Vtc, cntb, Pob, Mlb);
    combine_kernel<<<8192, 256, 0, stream>>>(Pob, Mlb, out);
}